// Round 1
// baseline (357.609 us; speedup 1.0000x reference)
//
#include <hip/hip_runtime.h>

#define SIG_LEN 2048
#define LM1F 2047.0f
#define N_ITER 15

// Linear-interp sample of one signal row at normalized position q (in [0,1]-ish).
// Mirrors reference _sample exactly (IEEE f32, no fp-contraction on critical ops).
__device__ __forceinline__ float sample_sig(const float* __restrict__ sig, float q) {
    float p = __fmul_rn(q, LM1F);
    p = fminf(fmaxf(p, 0.0f), LM1F);      // clip to [0, 2047]
    float fl = floorf(p);
    float cl = ceilf(p);
    int il = (int)fl;                      // in [0,2047] by construction
    int ir = (int)cl;                      // ceil(p) <= 2047 since p <= 2047
    float wr = __fsub_rn(p, fl);
    float vl = sig[il];
    float vr = sig[ir];
    // (1 - wr) * vl + wr * vr, no fma contraction
    return __fadd_rn(__fmul_rn(__fsub_rn(1.0f, wr), vl), __fmul_rn(wr, vr));
}

// One eps-scale's contribution to (g, c). Constants are compile-time.
__device__ __forceinline__ void fd_contrib(const float* __restrict__ sig, float pos,
                                           float eps, float one_m_eps, float w,
                                           float two_eps, float eps_sq,
                                           float& g, float& c) {
    float pc = fminf(fmaxf(pos, eps), one_m_eps);          // clip(positions, eps, 1-eps)
    float v  = sample_sig(sig, pc);
    float vl = sample_sig(sig, __fsub_rn(pc, eps));
    float vr = sample_sig(sig, __fadd_rn(pc, eps));
    // g += w*(vr-vl)/(2*eps)
    g = __fadd_rn(g, __fmul_rn(w, __fsub_rn(vr, vl)) / two_eps);
    // c += w*(vr+vl-2*v)/(eps*eps)   -> ((vr+vl) - 2*v)
    float t = __fsub_rn(__fadd_rn(vr, vl), __fmul_rn(2.0f, v));
    c = __fadd_rn(c, __fmul_rn(w, t) / eps_sq);
}

__global__ __launch_bounds__(256) void refine_kernel(
    const float* __restrict__ init,
    const float* __restrict__ signals,
    float* __restrict__ out, int n)
{
    int idx = blockIdx.x * blockDim.x + threadIdx.x;
    if (idx >= n) return;

    int row = idx / 3;
    const float* __restrict__ sig = signals + (size_t)row * SIG_LEN;

    float pos = init[idx];
    float ss = 0.01f;   // step_size, decays by 0.9 each iteration (stop never triggers: see analysis)

    // max_step table: 0.2 * 0.9^t, double-rounded to f32 (matches f32 pow to <=1 ulp;
    // only matters when step hits the clip, where a 1-ulp diff is ~1e-8 in position).
    const float ms_tab[N_ITER] = {
        0.2f, 0.18f, 0.162f, 0.1458f, 0.13122f,
        0.118098f, 0.1062882f, 0.09565938f, 0.086093442f, 0.0774840978f,
        0.06973568802f, 0.062762119218f, 0.0564859072962f, 0.05083731656658f,
        0.045753584909922f
    };

    #pragma unroll
    for (int it = 0; it < N_ITER; ++it) {
        float g = 0.0f, c = 0.0f;
        // eps order matters for accumulation rounding: 0.001, 0.003, 0.01
        fd_contrib(sig, pos, 0.001f, 0.999f, 0.5f, 0.002f, 1e-06f, g, c);
        fd_contrib(sig, pos, 0.003f, 0.997f, 0.3f, 0.006f, 9e-06f, g, c);
        fd_contrib(sig, pos, 0.01f,  0.99f,  0.2f, 0.02f,  1e-04f, g, c);

        c = fminf(fmaxf(c, -1000.0f), 1000.0f);
        float step = (-g) / __fadd_rn(fabsf(c), 1e-06f);
        float ms = ms_tab[it];
        step = fminf(fmaxf(step, -ms), ms);
        pos = fminf(fmaxf(__fadd_rn(pos, __fmul_rn(ss, step)), 0.0f), 1.0f);
        ss = __fmul_rn(ss, 0.9f);
    }

    out[idx] = pos;
}

extern "C" void kernel_launch(void* const* d_in, const int* in_sizes, int n_in,
                              void* d_out, int out_size, void* d_ws, size_t ws_size,
                              hipStream_t stream) {
    const float* init    = (const float*)d_in[0];   // (32768, 3) f32
    const float* signals = (const float*)d_in[1];   // (32768, 2048) f32
    float* out = (float*)d_out;                     // (32768, 3) f32

    int n = out_size;                               // 98304
    int block = 256;
    int grid = (n + block - 1) / block;
    refine_kernel<<<grid, block, 0, stream>>>(init, signals, out, n);
}

// Round 2
// 321.201 us; speedup vs baseline: 1.1133x; 1.1133x over previous
//
#include <hip/hip_runtime.h>

#define SIG_LEN 2048
#define LM1F 2047.0f
#define N_ITER 15
#define TPB 128          // tasks (= threads) per block
#define WIN 96           // window floats per task (±47/+48 around floor(init*2047))
#define WPAD 97          // padded LDS stride; 97 % 32 == 1 -> bank-decorrelated

// Linear-interp sample out of the task's LDS window. Exactly mirrors reference
// _sample in IEEE f32 (no fp-contraction): p=clip(q*2047,0,2047), il=floor,
// ir=ceil (== il + (p>fl)), lerp. Window bound proof: |Δpos|/iter <= 0.002*0.81^it
// (sum 0.01008) + eps reach 0.01 -> ±41.1 idx (+1 floor/ceil) < ±47 window margin.
__device__ __forceinline__ float sample_lds(const float* __restrict__ w, float q) {
    float p = __fmul_rn(q, LM1F);
    p = fminf(fmaxf(p, 0.0f), LM1F);
    float fl = floorf(p);
    int il = (int)fl;                  // global index; caller's w is pre-offset by -base
    int inc = (p > fl) ? 1 : 0;        // ceil(p) - floor(p) for p in [0,2047]
    float wr = __fsub_rn(p, fl);
    float vl = w[il];
    float vr = w[il + inc];
    return __fadd_rn(__fmul_rn(__fsub_rn(1.0f, wr), vl), __fmul_rn(wr, vr));
}

__device__ __forceinline__ void fd_contrib(const float* __restrict__ w, float pos,
                                           float eps, float one_m_eps, float wgt,
                                           float two_eps, float eps_sq,
                                           float& g, float& c) {
    float pc = fminf(fmaxf(pos, eps), one_m_eps);          // clip(positions, eps, 1-eps)
    float v  = sample_lds(w, pc);
    float vl = sample_lds(w, __fsub_rn(pc, eps));
    float vr = sample_lds(w, __fadd_rn(pc, eps));
    g = __fadd_rn(g, __fmul_rn(wgt, __fsub_rn(vr, vl)) / two_eps);
    float t = __fsub_rn(__fadd_rn(vr, vl), __fmul_rn(2.0f, v));
    c = __fadd_rn(c, __fmul_rn(wgt, t) / eps_sq);
}

__global__ __launch_bounds__(TPB) void refine_kernel(
    const float* __restrict__ init,
    const float* __restrict__ signals,
    float* __restrict__ out)
{
    __shared__ float win[TPB * WPAD];   // ~49.7 KB -> 3 blocks/CU, 768 blocks = 3/CU exact
    __shared__ int   wbase[TPB];

    const int tid   = threadIdx.x;
    const int task0 = blockIdx.x * TPB;
    const int task  = task0 + tid;      // n = 98304 = 768 * 128 exactly, no guard needed

    // ---- phase 1: per-task window base ----
    const float p0 = init[task];
    float pp = fminf(fmaxf(__fmul_rn(p0, LM1F), 0.0f), LM1F);
    int base = (int)floorf(pp) - 47;
    base = min(max(base, 0), SIG_LEN - WIN);
    wbase[tid] = base;
    __syncthreads();

    // ---- phase 2: cooperative coalesced staging (lane i -> word i of a task's
    // contiguous 384B segment; a wave reads 256 contiguous bytes per instr) ----
    #pragma unroll 4
    for (int k = tid; k < TPB * WIN; k += TPB) {
        int t = k / WIN;                     // const-div -> magic mul
        int e = k - t * WIN;
        int row = (task0 + t) / 3;
        win[t * WPAD + e] = signals[(size_t)row * SIG_LEN + (wbase[t] + e)];
    }
    __syncthreads();

    // ---- phase 3: all 15 iterations out of LDS ----
    // Pre-offset pointer so sample_lds can index with the global il directly.
    const float* __restrict__ w = &win[tid * WPAD] - base;

    float pos = p0;
    float ss = 0.01f;

    const float ms_tab[N_ITER] = {
        0.2f, 0.18f, 0.162f, 0.1458f, 0.13122f,
        0.118098f, 0.1062882f, 0.09565938f, 0.086093442f, 0.0774840978f,
        0.06973568802f, 0.062762119218f, 0.0564859072962f, 0.05083731656658f,
        0.045753584909922f
    };

    #pragma unroll
    for (int it = 0; it < N_ITER; ++it) {
        float g = 0.0f, c = 0.0f;
        fd_contrib(w, pos, 0.001f, 0.999f, 0.5f, 0.002f, 1e-06f, g, c);
        fd_contrib(w, pos, 0.003f, 0.997f, 0.3f, 0.006f, 9e-06f, g, c);
        fd_contrib(w, pos, 0.01f,  0.99f,  0.2f, 0.02f,  1e-04f, g, c);

        c = fminf(fmaxf(c, -1000.0f), 1000.0f);
        float step = (-g) / __fadd_rn(fabsf(c), 1e-06f);
        float ms = ms_tab[it];
        step = fminf(fmaxf(step, -ms), ms);
        pos = fminf(fmaxf(__fadd_rn(pos, __fmul_rn(ss, step)), 0.0f), 1.0f);
        ss = __fmul_rn(ss, 0.9f);
    }

    out[task] = pos;
}

extern "C" void kernel_launch(void* const* d_in, const int* in_sizes, int n_in,
                              void* d_out, int out_size, void* d_ws, size_t ws_size,
                              hipStream_t stream) {
    const float* init    = (const float*)d_in[0];   // (32768, 3) f32
    const float* signals = (const float*)d_in[1];   // (32768, 2048) f32
    float* out = (float*)d_out;                     // (32768, 3) f32

    int n = out_size;                               // 98304
    int grid = n / TPB;                             // 768
    refine_kernel<<<grid, TPB, 0, stream>>>(init, signals, out);
}